// Round 1
// baseline (732.665 us; speedup 1.0000x reference)
//
#include <hip/hip_runtime.h>

// Problem constants
#define BDIM 8
#define NPTS 8192
#define MPTS 2048
#define CF 256            // channels per feature set (C == CP == D1 == D2 == 256)
#define NSAMP 65536.0f    // B*N samples per BN channel

// ---------------------------------------------------------------------------
// three_nn: for each query point, find 3 nearest known points.
// Distance computed EXACTLY like the reference: (sq_u + sq_k) - 2*dot, fp32,
// no fma contraction, strict-< insertion so earlier index wins ties (top_k).
// ---------------------------------------------------------------------------
__global__ __launch_bounds__(256)
void three_nn_kernel(const float* __restrict__ xyz, const float* __restrict__ xyz_prev,
                     int* __restrict__ idx_out, float* __restrict__ wgt_out) {
  __shared__ float px[MPTS], py[MPTS], pz[MPTS], sk[MPTS];
  const int b = blockIdx.y;
  const int tid = threadIdx.x;
  for (int j = tid; j < MPTS; j += 256) {
    float x = xyz_prev[((size_t)b*MPTS + j)*3 + 0];
    float y = xyz_prev[((size_t)b*MPTS + j)*3 + 1];
    float z = xyz_prev[((size_t)b*MPTS + j)*3 + 2];
    px[j] = x; py[j] = y; pz[j] = z;
    sk[j] = __fadd_rn(__fadd_rn(__fmul_rn(x,x), __fmul_rn(y,y)), __fmul_rn(z,z));
  }
  __syncthreads();
  const int n = blockIdx.x*256 + tid;
  const size_t qoff = ((size_t)b*NPTS + n)*3;
  const float qx = xyz[qoff], qy = xyz[qoff+1], qz = xyz[qoff+2];
  const float squ = __fadd_rn(__fadd_rn(__fmul_rn(qx,qx), __fmul_rn(qy,qy)), __fmul_rn(qz,qz));

  float d0 = 3.4e38f, d1 = 3.4e38f, d2v = 3.4e38f;
  int j0 = 0, j1 = 0, j2 = 0;
  for (int m = 0; m < MPTS; ++m) {
    float dot = __fadd_rn(__fadd_rn(__fmul_rn(qx,px[m]), __fmul_rn(qy,py[m])), __fmul_rn(qz,pz[m]));
    float dd  = __fsub_rn(__fadd_rn(squ, sk[m]), __fmul_rn(2.0f, dot));
    if (dd < d2v) {
      if (dd < d1) {
        d2v = d1; j2 = j1;
        if (dd < d0) { d1 = d0; j1 = j0; d0 = dd; j0 = m; }
        else         { d1 = dd; j1 = m; }
      } else { d2v = dd; j2 = m; }
    }
  }
  const float s0 = sqrtf(fmaxf(d0, 0.f));
  const float s1 = sqrtf(fmaxf(d1, 0.f));
  const float s2 = sqrtf(fmaxf(d2v, 0.f));
  const float i0 = 1.f/(s0 + 1e-8f), i1 = 1.f/(s1 + 1e-8f), i2 = 1.f/(s2 + 1e-8f);
  const float sum = i0 + i1 + i2;
  const size_t o = ((size_t)b*NPTS + n)*3;
  idx_out[o] = j0; idx_out[o+1] = j1; idx_out[o+2] = j2;
  wgt_out[o] = i0/sum; wgt_out[o+1] = i1/sum; wgt_out[o+2] = i2/sum;
}

// ---------------------------------------------------------------------------
// three_interpolate: new_feat[b,c,n] = sum_k wgt[b,n,k] * fp[b,c,idx[b,n,k]]
// ---------------------------------------------------------------------------
__global__ __launch_bounds__(256)
void interp_kernel(const float* __restrict__ fp, const int* __restrict__ idx,
                   const float* __restrict__ wgt, float* __restrict__ out) {
  const int n = blockIdx.x*256 + threadIdx.x;
  const int c = blockIdx.y, b = blockIdx.z;
  const size_t p = ((size_t)b*NPTS + n)*3;
  const int i0 = idx[p], i1 = idx[p+1], i2 = idx[p+2];
  const float w0 = wgt[p], w1 = wgt[p+1], w2 = wgt[p+2];
  const float* frow = fp + ((size_t)b*CF + c)*MPTS;
  out[((size_t)b*CF + c)*NPTS + n] = frow[i0]*w0 + frow[i1]*w1 + frow[i2]*w2;
}

// ---------------------------------------------------------------------------
// W transpose: src [O][I] -> dst [I][O] so GEMM staging loads are contiguous.
// ---------------------------------------------------------------------------
__global__ void transpose_kernel(const float* __restrict__ src, float* __restrict__ dst,
                                 int O, int I) {
  int t = blockIdx.x*256 + threadIdx.x;
  if (t >= O*I) return;
  int i = t % I, o = t / I;
  dst[i*O + o] = src[t];
}

// ---------------------------------------------------------------------------
// Register-blocked fp32 GEMM: Y[b,o,n] = sum_i Wt[i][o] * X[b,i,n] + bias[o]
// 128x128 tile, BK=16, 256 threads, 8x8 accum/thread.
// MODE 1: X rows [0,256) from Xa (interpolated), [256,512) from Xb (features).
// MODE 2: X = Xa with fused BN1+ReLU applied on load (scl/shf per row).
// Fused epilogue: per-channel partial sum/sumsq for BatchNorm via atomics.
// ---------------------------------------------------------------------------
template<int KDIM, int MODE>
__global__ __launch_bounds__(256, 2)
void gemm_bn_kernel(const float* __restrict__ Wt, const float* __restrict__ bias,
                    const float* __restrict__ Xa, const float* __restrict__ Xb,
                    const float* __restrict__ scl, const float* __restrict__ shf,
                    float* __restrict__ Y, float* __restrict__ bsum, float* __restrict__ bsq) {
  __shared__ float Ws[16][128];
  __shared__ float Xs[16][128];
  const int tid = threadIdx.x;
  const int tx = tid & 15, ty = tid >> 4;
  const int n0 = blockIdx.x * 128;
  const int o0 = blockIdx.y * 128;
  const int b  = blockIdx.z;
  const int c8 = tx * 8;

  float acc[8][8];
  #pragma unroll
  for (int i = 0; i < 8; ++i)
    #pragma unroll
    for (int j = 0; j < 8; ++j) acc[i][j] = 0.f;

  for (int kt = 0; kt < KDIM/16; ++kt) {
    const int kg = kt*16 + ty;           // global k row this thread stages
    // --- stage W tile (issue global loads before the barrier) ---
    const float* wsrc = Wt + (size_t)kg*CF + o0 + c8;
    float4 w0 = *(const float4*)wsrc;
    float4 w1 = *(const float4*)(wsrc + 4);
    // --- stage X tile ---
    float4 x0, x1;
    if (MODE == 1) {
      const float* base = (kg < CF)
        ? (Xa + ((size_t)b*CF + kg)*NPTS)
        : (Xb + ((size_t)b*CF + (kg - CF))*NPTS);
      x0 = *(const float4*)(base + n0 + c8);
      x1 = *(const float4*)(base + n0 + c8 + 4);
    } else {
      const float* base = Xa + ((size_t)b*CF + kg)*NPTS;
      x0 = *(const float4*)(base + n0 + c8);
      x1 = *(const float4*)(base + n0 + c8 + 4);
      const float s = scl[kg], h = shf[kg];
      x0.x = fmaxf(fmaf(x0.x, s, h), 0.f);
      x0.y = fmaxf(fmaf(x0.y, s, h), 0.f);
      x0.z = fmaxf(fmaf(x0.z, s, h), 0.f);
      x0.w = fmaxf(fmaf(x0.w, s, h), 0.f);
      x1.x = fmaxf(fmaf(x1.x, s, h), 0.f);
      x1.y = fmaxf(fmaf(x1.y, s, h), 0.f);
      x1.z = fmaxf(fmaf(x1.z, s, h), 0.f);
      x1.w = fmaxf(fmaf(x1.w, s, h), 0.f);
    }
    __syncthreads();                     // previous compute done before overwrite
    *(float4*)&Ws[ty][c8]     = w0;
    *(float4*)&Ws[ty][c8 + 4] = w1;
    *(float4*)&Xs[ty][c8]     = x0;
    *(float4*)&Xs[ty][c8 + 4] = x1;
    __syncthreads();
    #pragma unroll
    for (int kk = 0; kk < 16; ++kk) {
      float a[8], bb[8];
      *(float4*)&a[0]  = *(const float4*)&Ws[kk][ty*8];
      *(float4*)&a[4]  = *(const float4*)&Ws[kk][ty*8 + 4];
      *(float4*)&bb[0] = *(const float4*)&Xs[kk][tx*8];
      *(float4*)&bb[4] = *(const float4*)&Xs[kk][tx*8 + 4];
      #pragma unroll
      for (int i = 0; i < 8; ++i)
        #pragma unroll
        for (int j = 0; j < 8; ++j)
          acc[i][j] = fmaf(a[i], bb[j], acc[i][j]);
    }
  }

  // --- epilogue: bias add, store, per-channel partial BN sums ---
  float ssum[8], ssq[8];
  #pragma unroll
  for (int r = 0; r < 8; ++r) {
    const int row = o0 + ty*8 + r;
    const float bv = bias[row];
    float v[8];
    float s = 0.f, q = 0.f;
    #pragma unroll
    for (int j = 0; j < 8; ++j) {
      v[j] = acc[r][j] + bv;
      s += v[j];
      q = fmaf(v[j], v[j], q);
    }
    float* dst = Y + ((size_t)b*CF + row)*NPTS + n0 + tx*8;
    *(float4*)dst       = make_float4(v[0], v[1], v[2], v[3]);
    *(float4*)(dst + 4) = make_float4(v[4], v[5], v[6], v[7]);
    ssum[r] = s; ssq[r] = q;
  }
  float* red = &Ws[0][0];                // reuse LDS (2048 floats >= 128*16)
  __syncthreads();
  #pragma unroll
  for (int r = 0; r < 8; ++r) red[(ty*8 + r)*16 + tx] = ssum[r];
  __syncthreads();
  if (tid < 128) {
    float t = 0.f;
    #pragma unroll
    for (int j = 0; j < 16; ++j) t += red[tid*16 + j];
    atomicAdd(&bsum[o0 + tid], t);
  }
  __syncthreads();
  #pragma unroll
  for (int r = 0; r < 8; ++r) red[(ty*8 + r)*16 + tx] = ssq[r];
  __syncthreads();
  if (tid < 128) {
    float t = 0.f;
    #pragma unroll
    for (int j = 0; j < 16; ++j) t += red[tid*16 + j];
    atomicAdd(&bsq[o0 + tid], t);
  }
}

// ---------------------------------------------------------------------------
// BN finalize: per-channel scale/shift from accumulated sum/sumsq.
// ---------------------------------------------------------------------------
__global__ void bn_finalize_kernel(const float* __restrict__ s, const float* __restrict__ q,
                                   const float* __restrict__ g, const float* __restrict__ beta,
                                   float* __restrict__ scl, float* __restrict__ shf) {
  const int o = threadIdx.x;   // 256 threads, 1 block
  const float inv_n = 1.0f / NSAMP;
  const float mean = s[o] * inv_n;
  const float var  = q[o] * inv_n - mean*mean;
  const float sc = g[o] * rsqrtf(var + 1e-5f);
  scl[o] = sc;
  shf[o] = beta[o] - mean * sc;
}

// ---------------------------------------------------------------------------
// Final BN2 + ReLU elementwise: out = max(y2*scl[o] + shf[o], 0)
// ---------------------------------------------------------------------------
__global__ __launch_bounds__(256)
void bn_apply_kernel(const float* __restrict__ Yin, const float* __restrict__ scl,
                     const float* __restrict__ shf, float* __restrict__ out) {
  const size_t t = (size_t)blockIdx.x*256 + threadIdx.x;
  const size_t base = t * 4;
  const int o = (int)((base / NPTS) & (CF - 1));
  float4 v = *(const float4*)(Yin + base);
  const float s = scl[o], h = shf[o];
  v.x = fmaxf(fmaf(v.x, s, h), 0.f);
  v.y = fmaxf(fmaf(v.y, s, h), 0.f);
  v.z = fmaxf(fmaf(v.z, s, h), 0.f);
  v.w = fmaxf(fmaf(v.w, s, h), 0.f);
  *(float4*)(out + base) = v;
}

// ---------------------------------------------------------------------------
// Launch. ws layout (bytes):
//   0        idx   int32[B*N*3]                 786432
//   786432   wgt   f32  [B*N*3]                 786432
//   1572864  bn    f32  [8*256] (sums+params)     8192
//   1581056  w1t   f32  [512*256]               524288
//   2105344  w2t   f32  [256*256]               262144
//   2367488  big   f32  [8*256*8192]          67108864  (new_feat, then y2)
// total ~66.3 MB
// ---------------------------------------------------------------------------
extern "C" void kernel_launch(void* const* d_in, const int* in_sizes, int n_in,
                              void* d_out, int out_size, void* d_ws, size_t ws_size,
                              hipStream_t stream) {
  const float* xyz           = (const float*)d_in[0];
  const float* xyz_prev      = (const float*)d_in[1];
  const float* features      = (const float*)d_in[2];
  const float* features_prev = (const float*)d_in[3];
  const float* w1    = (const float*)d_in[4];
  const float* b1    = (const float*)d_in[5];
  const float* g1    = (const float*)d_in[6];
  const float* beta1 = (const float*)d_in[7];
  const float* w2    = (const float*)d_in[8];
  const float* b2    = (const float*)d_in[9];
  const float* g2    = (const float*)d_in[10];
  const float* beta2 = (const float*)d_in[11];
  float* out = (float*)d_out;

  char* ws = (char*)d_ws;
  int*   idxb = (int*)ws;
  float* wgtb = (float*)(ws + 786432);
  float* bn   = (float*)(ws + 1572864);
  float* w1t  = (float*)(ws + 1581056);
  float* w2t  = (float*)(ws + 2105344);
  float* big  = (float*)(ws + 2367488);

  float* bn1_sum = bn;        float* bn1_sq  = bn + 256;
  float* bn2_sum = bn + 512;  float* bn2_sq  = bn + 768;
  float* bn1_scl = bn + 1024; float* bn1_shf = bn + 1280;
  float* bn2_scl = bn + 1536; float* bn2_shf = bn + 1792;

  // zero the BN accumulators (ws is poisoned before every launch)
  hipMemsetAsync(bn, 0, 4096, stream);

  transpose_kernel<<<(256*512 + 255)/256, 256, 0, stream>>>(w1, w1t, 256, 512);
  transpose_kernel<<<(256*256 + 255)/256, 256, 0, stream>>>(w2, w2t, 256, 256);

  three_nn_kernel<<<dim3(NPTS/256, BDIM), 256, 0, stream>>>(xyz, xyz_prev, idxb, wgtb);

  interp_kernel<<<dim3(NPTS/256, CF, BDIM), 256, 0, stream>>>(features_prev, idxb, wgtb, big);

  // layer 1: y1 = w1 @ [new_feat; features] + b1  -> d_out, BN1 partials
  gemm_bn_kernel<512, 1><<<dim3(NPTS/128, 2, BDIM), 256, 0, stream>>>(
      w1t, b1, big, features, nullptr, nullptr, out, bn1_sum, bn1_sq);
  bn_finalize_kernel<<<1, 256, 0, stream>>>(bn1_sum, bn1_sq, g1, beta1, bn1_scl, bn1_shf);

  // layer 2: y2 = w2 @ relu(bn1(y1)) + b2 -> big, BN2 partials
  gemm_bn_kernel<256, 2><<<dim3(NPTS/128, 2, BDIM), 256, 0, stream>>>(
      w2t, b2, out, nullptr, bn1_scl, bn1_shf, big, bn2_sum, bn2_sq);
  bn_finalize_kernel<<<1, 256, 0, stream>>>(bn2_sum, bn2_sq, g2, beta2, bn2_scl, bn2_shf);

  // final: out = relu(bn2(y2))
  bn_apply_kernel<<<(BDIM*CF*NPTS)/(256*4), 256, 0, stream>>>(big, bn2_scl, bn2_shf, out);
}